// Round 9
// baseline (165.530 us; speedup 1.0000x reference)
//
#include <hip/hip_runtime.h>
#include <hip/hip_bf16.h>
#include <math.h>

// CrossAttention: B=2, S=4096, DIM=256, NH=8, DH=32.
// R22 = R21 with occupancy raised the RIGHT way. R21's ks 4->2 LOWERED
// residency (demand 4 blocks/CU < LDS capacity 5; occupancy 38->31%, flash
// 65->74us): the 5+3 split at ks=4 was better, not worse. Now: ks=4 restored
// (grid 2048, 8 blocks/CU demand) + LDS diet 30208->24064 B so SIX blocks/CU
// fit: Vt stride 152->136 shorts (still 8-short aligned, 2-way bank alias =
// free), Pb[8][640]->[4][640] (one P row/wave, reused across q-tiles — safe:
// per-wave LDS ops are in-order, q-tile1's write can't pass q-tile0's read;
// same mechanism already orders each tile's write->read pair). 6+2 residency.
// KEPT: fp16 internal path (absmax 3.05e-5), Pb-LDS P-redistribution,
// all-modeled ops.
// LESSONS: residency = min(grid demand, LDS capacity); raising capacity only
// helps if demand exists [R21]; permlane in-register P redistribution loses
// to Pb-LDS (serial hazard chain vs LDS-decoupled stages) [R18/R19]; never
// set launch_bounds min-waves below natural VGPR fit [R14/R17]; inline-asm
// producers + cross-lane/MFMA consumers = corruption [R16]; hip bf16 cvt is
// software, fp16 cvt native [R18]; staged-LDS+barriers > direct-global [R11];
// SQ_LDS_BANK_CONFLICT op-width-inherent [R10]; strides mult of 8 shorts
// [R3/R4/R6]; flash K/V via LDS [R5].

#define SCALE 0.17677669529663687f   // 32^-0.5
#define LOG2E 1.4426950408889634f

typedef __attribute__((ext_vector_type(8))) short short8;
typedef __attribute__((ext_vector_type(8))) _Float16 half8;
typedef __attribute__((ext_vector_type(4))) float f32x4;

static __device__ __forceinline__ float fexp2(float x) {
#if __has_builtin(__builtin_amdgcn_exp2f)
    return __builtin_amdgcn_exp2f(x);
#else
    return exp2f(x);
#endif
}
// Pack two f32 -> packed fp16x2 via native, compiler-modeled converts
// (v_cvt_f16_f32 x2 + v_pack_b32_f16; RNE; hazard-safe, no inline asm).
static __device__ __forceinline__ unsigned int pk_f16(float a, float b) {
    union { _Float16 h[2]; unsigned int u; } x;
    x.h[0] = (_Float16)a; x.h[1] = (_Float16)b;
    return x.u;
}
static __device__ __forceinline__ unsigned short f2h(float x) {
    _Float16 h = (_Float16)x;
    union { _Float16 h; unsigned short s; } u; u.h = h;
    return u.s;
}
static __device__ __forceinline__ float h2f(unsigned short s) {
    union { _Float16 h; unsigned short s; } u; u.s = s;
    return (float)u.h;
}

// -------------------------------------------------- K0: W^T -> fp16 prep
__global__ __launch_bounds__(256) void prep(
    const float* __restrict__ Wq, const float* __restrict__ Wkv,
    const float* __restrict__ Wp, unsigned short* __restrict__ wfp)
{
    __shared__ float T[64][68];
    const int bb = blockIdx.x, t = threadIdx.x;
    const int mat = bb >> 4, tile = bb & 15;
    const int kr0 = (tile >> 2) * 64;
    const int nc0 = (tile & 3) * 64;
    const float* src; int ldw, cb; float sc = 1.f;
    if (mat == 0)      { src = Wq;  ldw = 256; cb = 0;   sc = SCALE * LOG2E; }
    else if (mat == 1) { src = Wkv; ldw = 512; cb = 0;   }
    else if (mat == 2) { src = Wkv; ldw = 512; cb = 256; }
    else               { src = Wp;  ldw = 256; cb = 0;   }
    {
        const int rl = t >> 4, c4 = (t & 15) * 4;
#pragma unroll
        for (int rr = 0; rr < 4; ++rr) {
            float4 v = *(const float4*)&src[(long long)(kr0 + rr * 16 + rl) * ldw + cb + nc0 + c4];
            T[rr * 16 + rl][c4 + 0] = v.x; T[rr * 16 + rl][c4 + 1] = v.y;
            T[rr * 16 + rl][c4 + 2] = v.z; T[rr * 16 + rl][c4 + 3] = v.w;
        }
    }
    __syncthreads();
    {
        const int nl = t >> 2, kl0 = (t & 3) * 16;
        const long long orow = (long long)(mat * 256 + nc0 + nl) * 256 + kr0 + kl0;
        union { unsigned short s[16]; uint4 u[2]; } ph;
#pragma unroll
        for (int j = 0; j < 16; ++j)
            ph.s[j] = f2h(T[kl0 + j][nl] * sc);
        *(uint4*)&wfp[orow] = ph.u[0];
        *(uint4*)&wfp[orow + 8] = ph.u[1];
    }
}

// ----------------------- K1: QKV fp16 MFMA GEMM, K/V fused per sim-tile
// grid (128, 8), block 256. by<4: Q (n0=by*64). by>=4: K+V (n0=(by-4)*64).
__global__ __launch_bounds__(256) void gemm_qkv(
    const float* __restrict__ query, const float* __restrict__ sim,
    const unsigned short* __restrict__ wfp,
    const float* __restrict__ bq, const float* __restrict__ bkv,
    unsigned short* __restrict__ qbuf, unsigned short* __restrict__ kbuf,
    unsigned short* __restrict__ vTb)
{
    __shared__ unsigned short Xs[64 * 40], WsA[64 * 40], WsB[64 * 40];

    const int t = threadIdx.x, wave = t >> 6, lane = t & 63;
    const int col = lane & 15, quad = lane >> 4;
    const int by = blockIdx.y;
    const bool isQ = (by < 4);
    const int n0 = (isQ ? by : by - 4) * 64;
    const int m0 = blockIdx.x * 64;
    const float* __restrict__ X = isQ ? query : sim;
    const int wrowA = (isQ ? 0 : 256) + n0;      // Wq or Wk rows
    const int wrowB = 512 + n0;                  // Wv rows (KV path only)
    const int srow = t >> 2, spart = (t & 3) * 8;

    const f32x4 zero = {0.f, 0.f, 0.f, 0.f};
    f32x4 accA[4] = {zero, zero, zero, zero};    // Q or K  (C[m=s][n=feat])
    f32x4 accV[4] = {zero, zero, zero, zero};    // V       (C[m=feat][n=s])

    for (int kt = 0; kt < 8; ++kt) {
        const int k0 = kt * 32;
        const float* xp = &X[(long long)(m0 + srow) * 256 + k0 + spart];
        float4 xa = *(const float4*)xp;
        float4 xb = *(const float4*)(xp + 4);
        float xv[8] = {xa.x, xa.y, xa.z, xa.w, xb.x, xb.y, xb.z, xb.w};
        union { unsigned short s[8]; uint4 u; } ph;
#pragma unroll
        for (int j = 0; j < 8; ++j) ph.s[j] = f2h(xv[j]);
        uint4 wa = *(const uint4*)&wfp[(long long)(wrowA + srow) * 256 + k0 + spart];
        uint4 wb;
        if (!isQ) wb = *(const uint4*)&wfp[(long long)(wrowB + srow) * 256 + k0 + spart];
        __syncthreads();
        *(uint4*)&Xs[srow * 40 + spart] = ph.u;
        *(uint4*)&WsA[srow * 40 + spart] = wa;
        if (!isQ) *(uint4*)&WsB[srow * 40 + spart] = wb;
        __syncthreads();

        half8 aX = *(const half8*)(Xs + (wave * 16 + col) * 40 + quad * 8);
#pragma unroll
        for (int nt = 0; nt < 4; ++nt) {
            half8 b = *(const half8*)(WsA + (nt * 16 + col) * 40 + quad * 8);
            accA[nt] = __builtin_amdgcn_mfma_f32_16x16x32_f16(aX, b, accA[nt], 0, 0, 0);
        }
        if (!isQ) {
            half8 aW = *(const half8*)(WsB + (wave * 16 + col) * 40 + quad * 8);
#pragma unroll
            for (int nt = 0; nt < 4; ++nt) {
                half8 b = *(const half8*)(Xs + (nt * 16 + col) * 40 + quad * 8);
                accV[nt] = __builtin_amdgcn_mfma_f32_16x16x32_f16(aW, b, accV[nt], 0, 0, 0);
            }
        }
    }

    if (isQ) {
#pragma unroll
        for (int nt = 0; nt < 4; ++nt) {
            int n = n0 + nt * 16 + col;
            int h = n >> 5, d = n & 31;
            float bias = bq[n] * (SCALE * LOG2E);
#pragma unroll
            for (int r = 0; r < 4; ++r) {
                int mg = m0 + wave * 16 + quad * 4 + r;
                int b = mg >> 12, sidx = mg & 4095;
                qbuf[((long long)(b * 8 + h) * 4096 + sidx) * 32 + d] = f2h(accA[nt][r] + bias);
            }
        }
    } else {
#pragma unroll
        for (int nt = 0; nt < 4; ++nt) {          // K epilogue
            int n = n0 + nt * 16 + col;
            int h = n >> 5, d = n & 31;
            float bias = bkv[n];
#pragma unroll
            for (int r = 0; r < 4; ++r) {
                int mg = m0 + wave * 16 + quad * 4 + r;
                int b = mg >> 12, sidx = mg & 4095;
                kbuf[((long long)(b * 8 + h) * 4096 + sidx) * 32 + d] = f2h(accA[nt][r] + bias);
            }
        }
#pragma unroll
        for (int nt = 0; nt < 4; ++nt) {          // V epilogue (transposed)
            int s = m0 + nt * 16 + col;
            int b = s >> 12, sidx = s & 4095;
#pragma unroll
            for (int r = 0; r < 4; ++r) {
                int dcol = n0 + wave * 16 + quad * 4 + r;
                int h = dcol >> 5, dd = dcol & 31;
                float bias = bkv[256 + dcol];
                vTb[((long long)((b * 8 + h) * 32 + dd)) * 4096 + sidx] = f2h(accV[nt][r] + bias);
            }
        }
    }
}

// ------------------------------------------------------------ K2: flash MFMA
// R22: Pb-LDS structure, fp16, ks=4, LDS diet 24064 B (Vt stride 136,
// Pb one row/wave) -> 6 blocks/CU. grid 2048 = ks(4) x bh(16) x qb(32).
__global__ __launch_bounds__(256) void flash_mfma(
    const unsigned short* __restrict__ qbuf,
    const unsigned short* __restrict__ kbuf,
    const unsigned short* __restrict__ vT,
    unsigned short* __restrict__ xpart, float* __restrict__ lpart)
{
    __shared__ unsigned short Ks[128 * 40];
    __shared__ unsigned short Vt[32 * 136];
    __shared__ unsigned short Pb[4][640];

    const int t = threadIdx.x;
    const int wave = t >> 6, lane = t & 63;
    const int col = lane & 15, quad = lane >> 4;
    const int qb = blockIdx.x & 31;
    const int bh = (blockIdx.x >> 5) & 15;
    const int ks = blockIdx.x >> 9;          // 0..3
    const int q0 = qb * 128 + wave * 32;
    const long long kvbase = (long long)bh * 4096 * 32;
    unsigned short* pb = Pb[wave];           // one row per wave, reused

    const half8 qf0 = *(const half8*)(qbuf + kvbase + (long long)(q0 + col) * 32 + quad * 8);
    const half8 qf1 = *(const half8*)(qbuf + kvbase + (long long)(q0 + 16 + col) * 32 + quad * 8);

    const f32x4 zero = {0.f, 0.f, 0.f, 0.f};
    f32x4 o00 = zero, o01 = zero, o10 = zero, o11 = zero;
    float l0 = 0.f, l1 = 0.f;

    const int krow = t >> 2, kpart = (t & 3) * 8;
    const int vrow = t >> 4, vpart = (t & 15) * 8;

    for (int kt0 = 0; kt0 < 8; ++kt0) {
        const int kt = ks * 8 + kt0;
        uint4 kg0 = *(const uint4*)(kbuf + kvbase + (long long)(kt * 128 + krow) * 32 + kpart);
        uint4 kg1 = *(const uint4*)(kbuf + kvbase + (long long)(kt * 128 + krow + 64) * 32 + kpart);
        uint4 vg0 = *(const uint4*)(vT + ((long long)(bh * 32 + vrow)) * 4096 + kt * 128 + vpart);
        uint4 vg1 = *(const uint4*)(vT + ((long long)(bh * 32 + vrow + 16)) * 4096 + kt * 128 + vpart);
        __syncthreads();
        *(uint4*)(Ks + krow * 40 + kpart) = kg0;
        *(uint4*)(Ks + (krow + 64) * 40 + kpart) = kg1;
        *(uint4*)(Vt + vrow * 136 + vpart) = vg0;
        *(uint4*)(Vt + (vrow + 16) * 136 + vpart) = vg1;
        __syncthreads();

#pragma unroll
        for (int sb = 0; sb < 4; ++sb) {
            const int kb = sb * 32;
            half8 a0 = *(const half8*)(Ks + (kb + col) * 40 + quad * 8);
            half8 a1 = *(const half8*)(Ks + (kb + 16 + col) * 40 + quad * 8);
            half8 v0 = *(const half8*)(Vt + col * 136 + kb + quad * 8);
            half8 v1 = *(const half8*)(Vt + (16 + col) * 136 + kb + quad * 8);
            // ---- q-tile 0
            {
                f32x4 c0 = __builtin_amdgcn_mfma_f32_16x16x32_f16(a0, qf0, zero, 0, 0, 0);
                f32x4 c1 = __builtin_amdgcn_mfma_f32_16x16x32_f16(a1, qf0, zero, 0, 0, 0);
                float p0 = fexp2(c0[0]), p1 = fexp2(c0[1]), p2 = fexp2(c0[2]), p3 = fexp2(c0[3]);
                float p4 = fexp2(c1[0]), p5 = fexp2(c1[1]), p6 = fexp2(c1[2]), p7 = fexp2(c1[3]);
                l0 += ((p0 + p1) + (p2 + p3)) + ((p4 + p5) + (p6 + p7));
                uint2 w0 = make_uint2(pk_f16(p0, p1), pk_f16(p2, p3));
                uint2 w1 = make_uint2(pk_f16(p4, p5), pk_f16(p6, p7));
                *(uint2*)(pb + col * 40 + quad * 4) = w0;
                *(uint2*)(pb + col * 40 + 16 + quad * 4) = w1;
                half8 pf = *(const half8*)(pb + col * 40 + quad * 8);
                o00 = __builtin_amdgcn_mfma_f32_16x16x32_f16(v0, pf, o00, 0, 0, 0);
                o01 = __builtin_amdgcn_mfma_f32_16x16x32_f16(v1, pf, o01, 0, 0, 0);
            }
            // ---- q-tile 1 (reuse a0,a1,v0,v1; reuse pb — per-wave LDS ops
            // are in-order, so this write cannot pass the read above)
            {
                f32x4 c0 = __builtin_amdgcn_mfma_f32_16x16x32_f16(a0, qf1, zero, 0, 0, 0);
                f32x4 c1 = __builtin_amdgcn_mfma_f32_16x16x32_f16(a1, qf1, zero, 0, 0, 0);
                float p0 = fexp2(c0[0]), p1 = fexp2(c0[1]), p2 = fexp2(c0[2]), p3 = fexp2(c0[3]);
                float p4 = fexp2(c1[0]), p5 = fexp2(c1[1]), p6 = fexp2(c1[2]), p7 = fexp2(c1[3]);
                l1 += ((p0 + p1) + (p2 + p3)) + ((p4 + p5) + (p6 + p7));
                uint2 w0 = make_uint2(pk_f16(p0, p1), pk_f16(p2, p3));
                uint2 w1 = make_uint2(pk_f16(p4, p5), pk_f16(p6, p7));
                *(uint2*)(pb + col * 40 + quad * 4) = w0;
                *(uint2*)(pb + col * 40 + 16 + quad * 4) = w1;
                half8 pf = *(const half8*)(pb + col * 40 + quad * 8);
                o10 = __builtin_amdgcn_mfma_f32_16x16x32_f16(v0, pf, o10, 0, 0, 0);
                o11 = __builtin_amdgcn_mfma_f32_16x16x32_f16(v1, pf, o11, 0, 0, 0);
            }
        }
    }

    l0 += __shfl_xor(l0, 16, 64); l0 += __shfl_xor(l0, 32, 64);
    l1 += __shfl_xor(l1, 16, 64); l1 += __shfl_xor(l1, 32, 64);

    const int b = bh >> 3, hh = bh & 7;
    unsigned short* xp = xpart + (long long)ks * 2097152;
    {
        unsigned short* rp = xp + ((long long)(b * 4096 + q0 + col)) * 256 + hh * 32;
        union { unsigned short s[4]; uint2 u; } pa, pb2;
#pragma unroll
        for (int r = 0; r < 4; ++r) { pa.s[r] = f2h(o00[r]); pb2.s[r] = f2h(o01[r]); }
        *(uint2*)(rp + quad * 4) = pa.u;
        *(uint2*)(rp + 16 + quad * 4) = pb2.u;
    }
    {
        unsigned short* rp = xp + ((long long)(b * 4096 + q0 + 16 + col)) * 256 + hh * 32;
        union { unsigned short s[4]; uint2 u; } pa, pb2;
#pragma unroll
        for (int r = 0; r < 4; ++r) { pa.s[r] = f2h(o10[r]); pb2.s[r] = f2h(o11[r]); }
        *(uint2*)(rp + quad * 4) = pa.u;
        *(uint2*)(rp + 16 + quad * 4) = pb2.u;
    }

    if (quad == 0)      lpart[ks * 65536 + bh * 4096 + q0 + col] = l0;
    else if (quad == 1) lpart[ks * 65536 + bh * 4096 + q0 + 16 + col] = l1;
}

// ------- K3: combine 4 fp16 partials + 1/l + out-proj. grid (128, 4).
__global__ __launch_bounds__(256) void gemm_outp(
    const unsigned short* __restrict__ xpart, const float* __restrict__ lpart,
    const unsigned short* __restrict__ wfp,
    const float* __restrict__ bp, float* __restrict__ out)
{
    __shared__ unsigned short XsH[64 * 40], XsL[64 * 40], Ws[64 * 40];

    const int t = threadIdx.x, wave = t >> 6, lane = t & 63;
    const int col = lane & 15, quad = lane >> 4;
    const int n0 = blockIdx.y * 64;
    const int m0 = blockIdx.x * 64;
    const int wrow0 = 768 + n0;
    const int srow = t >> 2, spart = (t & 3) * 8;
    const int r = m0 + srow;
    const int bidx = r >> 12, s = r & 4095;

    const f32x4 zero = {0.f, 0.f, 0.f, 0.f};
    f32x4 acc[4] = {zero, zero, zero, zero};

    for (int kt = 0; kt < 8; ++kt) {
        const int k0 = kt * 32;
        float lsum = lpart[(bidx * 8 + kt) * 4096 + s]
                   + lpart[65536 + (bidx * 8 + kt) * 4096 + s]
                   + lpart[131072 + (bidx * 8 + kt) * 4096 + s]
                   + lpart[196608 + (bidx * 8 + kt) * 4096 + s];
        const float linv = 1.f / lsum;

        union { unsigned short s4[8]; uint4 u; } p[4];
#pragma unroll
        for (int ss = 0; ss < 4; ++ss)
            p[ss].u = *(const uint4*)&xpart[(long long)ss * 2097152 +
                                            (long long)r * 256 + k0 + spart];
        union { unsigned short s4[8]; uint4 u; } ph, pl;
#pragma unroll
        for (int j = 0; j < 8; ++j) {
            float xv = (h2f(p[0].s4[j]) + h2f(p[1].s4[j]) +
                        h2f(p[2].s4[j]) + h2f(p[3].s4[j])) * linv;
            unsigned short h = f2h(xv);
            ph.s4[j] = h;
            pl.s4[j] = f2h(xv - h2f(h));
        }
        uint4 wh = *(const uint4*)&wfp[(long long)(wrow0 + srow) * 256 + k0 + spart];
        __syncthreads();
        *(uint4*)&XsH[srow * 40 + spart] = ph.u;
        *(uint4*)&XsL[srow * 40 + spart] = pl.u;
        *(uint4*)&Ws[srow * 40 + spart] = wh;
        __syncthreads();

        half8 a_h = *(const half8*)(XsH + (wave * 16 + col) * 40 + quad * 8);
        half8 a_l = *(const half8*)(XsL + (wave * 16 + col) * 40 + quad * 8);
#pragma unroll
        for (int nt = 0; nt < 4; ++nt) {
            half8 b = *(const half8*)(Ws + (nt * 16 + col) * 40 + quad * 8);
            acc[nt] = __builtin_amdgcn_mfma_f32_16x16x32_f16(a_h, b, acc[nt], 0, 0, 0);
            acc[nt] = __builtin_amdgcn_mfma_f32_16x16x32_f16(a_l, b, acc[nt], 0, 0, 0);
        }
    }

#pragma unroll
    for (int nt = 0; nt < 4; ++nt) {
        int n = n0 + nt * 16 + col;
        float bias = bp[n];
#pragma unroll
        for (int rr = 0; rr < 4; ++rr) {
            int mg = m0 + wave * 16 + quad * 4 + rr;
            out[(long long)mg * 256 + n] = acc[nt][rr] + bias;
        }
    }
}

extern "C" void kernel_launch(void* const* d_in, const int* in_sizes, int n_in,
                              void* d_out, int out_size, void* d_ws, size_t ws_size,
                              hipStream_t stream) {
    const float* query = (const float*)d_in[0];
    const float* sim   = (const float*)d_in[1];
    const float* Wq    = (const float*)d_in[2];
    const float* bq    = (const float*)d_in[3];
    const float* Wkv   = (const float*)d_in[4];
    const float* bkv   = (const float*)d_in[5];
    const float* Wp    = (const float*)d_in[6];
    const float* bp    = (const float*)d_in[7];
    float* out = (float*)d_out;

    unsigned short* wsb = (unsigned short*)d_ws;
    unsigned short* qbuf = wsb;                        // 2,097,152 shorts
    unsigned short* kbuf = wsb + 2097152;
    unsigned short* vT   = wsb + 4194304;              // ends 6,291,456
    unsigned short* wfp  = wsb + 6291456;              // 262,144 fp16
    unsigned short* xpart = wsb + 6553600;             // 4 x 2,097,152 fp16
    float* lpart = (float*)(wsb + 14942208);           // 4 x 65,536 fp32

    prep      <<<dim3(64),     256, 0, stream>>>(Wq, Wkv, Wp, wfp);
    gemm_qkv  <<<dim3(128, 8), 256, 0, stream>>>(query, sim, wfp, bq, bkv,
                                                 qbuf, kbuf, vT);
    flash_mfma<<<dim3(2048),   256, 0, stream>>>(qbuf, kbuf, vT, xpart, lpart);
    gemm_outp <<<dim3(128, 4), 256, 0, stream>>>(xpart, lpart, wfp, bp, out);
}